// Round 1
// baseline (1288.508 us; speedup 1.0000x reference)
//
#include <hip/hip_runtime.h>
#include <hip/hip_bf16.h>

#define NN 65536
#define NE 1048576

__device__ __forceinline__ float bcast(float v, int l) {
    return __int_as_float(__builtin_amdgcn_readlane(__float_as_int(v), l));
}
__device__ __forceinline__ float lrelu(float x) { return x > 0.f ? x : 0.01f * x; }
__device__ __forceinline__ float frelu(float x) { return x > 0.f ? x : 0.f; }

// ---- combined weights: Wda = W_dst@A1, Wsa = W_src@A1 ----
__global__ void k_prep(const float* __restrict__ Wdst, const float* __restrict__ Wsrc,
                       const float* __restrict__ A1, float* __restrict__ Wda,
                       float* __restrict__ Wsa) {
    int o = blockIdx.x * 256 + threadIdx.x;           // 0..8191
    const float* Wsel = (o < 4096) ? Wdst : Wsrc;
    float* Osel = (o < 4096) ? Wda : Wsa;
    int oo = o & 4095;
    int r = oo >> 6, c = oo & 63;
    float acc = 0.f;
#pragma unroll
    for (int k = 0; k < 64; ++k) acc += Wsel[r * 64 + k] * A1[k * 64 + c];
    Osel[oo] = acc;
}

// ---- h = relu(x @ W_in + b_in) ----
__global__ void __launch_bounds__(256) k_h(const float* __restrict__ x,
                                           const float* __restrict__ Win,
                                           const float* __restrict__ bin,
                                           float* __restrict__ h) {
    __shared__ float W[4096];
    for (int idx = threadIdx.x; idx < 4096; idx += 256) W[idx] = Win[idx];
    __syncthreads();
    int wave = threadIdx.x >> 6, lane = threadIdx.x & 63;
    int n = blockIdx.x * 4 + wave;
    float xv = x[n * 64 + lane];
    float acc = bin[lane];
#pragma unroll
    for (int k = 0; k < 64; ++k) acc += bcast(xv, k) * W[k * 64 + lane];
    h[n * 64 + lane] = frelu(acc);
}

// ---- v = h@W_lin ; ad1 = h@Wda + a1 ; as1 = h@Wsa ; q = pos@P1 ----
__global__ void __launch_bounds__(256) k_node(const float* __restrict__ h,
                                              const float* __restrict__ pos,
                                              const float* __restrict__ Wlin,
                                              const float* __restrict__ Wda,
                                              const float* __restrict__ Wsa,
                                              const float* __restrict__ P1,
                                              const float* __restrict__ a1,
                                              float* __restrict__ v, float* __restrict__ ad1,
                                              float* __restrict__ as1, float* __restrict__ q) {
    __shared__ float Wl[4096], Wd[4096], Ws[4096], P[192];
    for (int idx = threadIdx.x; idx < 4096; idx += 256) {
        Wl[idx] = Wlin[idx]; Wd[idx] = Wda[idx]; Ws[idx] = Wsa[idx];
    }
    if (threadIdx.x < 192) P[threadIdx.x] = P1[threadIdx.x];
    __syncthreads();
    int wave = threadIdx.x >> 6, lane = threadIdx.x & 63;
    int n = blockIdx.x * 4 + wave;
    float hv = h[n * 64 + lane];
    float av = 0.f, bv = a1[lane], cv = 0.f;
#pragma unroll
    for (int k = 0; k < 64; ++k) {
        float s = bcast(hv, k);
        av += s * Wl[k * 64 + lane];
        bv += s * Wd[k * 64 + lane];
        cv += s * Ws[k * 64 + lane];
    }
    v[n * 64 + lane] = av;
    ad1[n * 64 + lane] = bv;
    as1[n * 64 + lane] = cv;
    float p0 = pos[n * 3 + 0], p1v = pos[n * 3 + 1], p2v = pos[n * 3 + 2];
    q[n * 64 + lane] = p0 * P[lane] + p1v * P[64 + lane] + p2v * P[128 + lane];
}

// ---- CSR build: histogram, scan, scatter ----
__global__ void k_hist(const int* __restrict__ ei, int* __restrict__ deg) {
    int e = blockIdx.x * 256 + threadIdx.x;
    atomicAdd(&deg[ei[NE + e]], 1);
}

__global__ void k_scan(const int* __restrict__ deg, int* __restrict__ off,
                       int* __restrict__ cur) {
    __shared__ int part[256];
    int t = threadIdx.x;
    int sum = 0;
    for (int r = 0; r < 256; ++r) sum += deg[t * 256 + r];
    part[t] = sum;
    __syncthreads();
    if (t == 0) {
        int run = 0;
        for (int b = 0; b < 256; ++b) { int tmp = part[b]; part[b] = run; run += tmp; }
    }
    __syncthreads();
    int run = part[t];
    for (int r = 0; r < 256; ++r) {
        int n = t * 256 + r;
        off[n] = run; cur[n] = run;
        run += deg[n];
    }
    if (t == 255) off[NN] = run;   // == NE
}

__global__ void k_scatter(const int* __restrict__ ei, int* __restrict__ cur,
                          int* __restrict__ srtj) {
    int e = blockIdx.x * 256 + threadIdx.x;
    int i = ei[NE + e];
    int slot = atomicAdd(&cur[i], 1);
    srtj[slot] = ei[e];
}

// ---- fused edge MLP + scatter-softmax + output GEMM; one wave per target node ----
__global__ void __launch_bounds__(256) k_edge(
    const float* __restrict__ q, const float* __restrict__ ad1, const float* __restrict__ as1,
    const float* __restrict__ v, const int* __restrict__ off, const int* __restrict__ srtj,
    const float* __restrict__ P2w, const float* __restrict__ p2b,
    const float* __restrict__ A1w, const float* __restrict__ A2w,
    const float* __restrict__ a2b, const float* __restrict__ p1b,
    const float* __restrict__ Wout, const float* __restrict__ bout,
    float* __restrict__ out) {
    __shared__ float WP2[4096], WA1[4096], WA2[4096];
    for (int idx = threadIdx.x; idx < 4096; idx += 256) {
        WP2[idx] = P2w[idx]; WA1[idx] = A1w[idx]; WA2[idx] = A2w[idx];
    }
    __syncthreads();
    int wave = threadIdx.x >> 6, lane = threadIdx.x & 63;
    int node = blockIdx.x * 4 + wave;
    float qi = q[node * 64 + lane] + p1b[lane];
    float adv = ad1[node * 64 + lane];
    float p2v = p2b[lane], a2v = a2b[lane];
    int s0 = off[node], s1 = off[node + 1];
    float num = 0.f, den = 0.f;
    for (int s = s0; s < s1; ++s) {
        int j = srtj[s];
        float u = lrelu(qi - q[j * 64 + lane]);
        float d = p2v;
#pragma unroll
        for (int k = 0; k < 64; ++k) d += bcast(u, k) * WP2[k * 64 + lane];
        d = lrelu(d);
        float t = adv - as1[j * 64 + lane];
#pragma unroll
        for (int k = 0; k < 64; ++k) t += bcast(d, k) * WA1[k * 64 + lane];
        t = frelu(t);
        float al = a2v;
#pragma unroll
        for (int k = 0; k < 64; ++k) al += bcast(t, k) * WA2[k * 64 + lane];
        al = frelu(al);
        float e = __expf(al);
        den += e;
        num += e * (v[j * 64 + lane] + d);
    }
    float o = num / (den + 1e-16f);
    float f = bout[lane];
#pragma unroll
    for (int k = 0; k < 64; ++k) f += bcast(o, k) * Wout[k * 64 + lane];
    out[node * 64 + lane] = frelu(f);
}

extern "C" void kernel_launch(void* const* d_in, const int* in_sizes, int n_in,
                              void* d_out, int out_size, void* d_ws, size_t ws_size,
                              hipStream_t stream) {
    const float* x    = (const float*)d_in[0];
    const float* pos  = (const float*)d_in[1];
    const int*   ei   = (const int*)d_in[2];
    const float* Win  = (const float*)d_in[3];
    const float* bin  = (const float*)d_in[4];
    const float* Wout = (const float*)d_in[5];
    const float* bout = (const float*)d_in[6];
    const float* Wlin = (const float*)d_in[7];
    const float* Wsrc = (const float*)d_in[8];
    const float* Wdst = (const float*)d_in[9];
    const float* P1   = (const float*)d_in[10];
    const float* p1   = (const float*)d_in[11];
    const float* P2   = (const float*)d_in[12];
    const float* p2   = (const float*)d_in[13];
    const float* A1   = (const float*)d_in[14];
    const float* a1   = (const float*)d_in[15];
    const float* A2   = (const float*)d_in[16];
    const float* a2   = (const float*)d_in[17];
    float* out = (float*)d_out;

    char* w = (char*)d_ws;
    float* Wda = (float*)w; w += 4096 * 4;
    float* Wsa = (float*)w; w += 4096 * 4;
    float* h   = (float*)w; w += (size_t)NN * 64 * 4;
    float* v   = (float*)w; w += (size_t)NN * 64 * 4;
    float* ad1 = (float*)w; w += (size_t)NN * 64 * 4;
    float* as1 = (float*)w; w += (size_t)NN * 64 * 4;
    float* q   = (float*)w; w += (size_t)NN * 64 * 4;
    int* deg   = (int*)w; w += (size_t)NN * 4;
    int* off   = (int*)w; w += (size_t)(NN + 1) * 4;
    int* cur   = (int*)w; w += (size_t)NN * 4;
    int* srtj  = (int*)w; w += (size_t)NE * 4;

    hipMemsetAsync(deg, 0, (size_t)NN * 4, stream);
    k_prep<<<32, 256, 0, stream>>>(Wdst, Wsrc, A1, Wda, Wsa);
    k_h<<<NN / 4, 256, 0, stream>>>(x, Win, bin, h);
    k_node<<<NN / 4, 256, 0, stream>>>(h, pos, Wlin, Wda, Wsa, P1, a1, v, ad1, as1, q);
    k_hist<<<NE / 256, 256, 0, stream>>>(ei, deg);
    k_scan<<<1, 256, 0, stream>>>(deg, off, cur);
    k_scatter<<<NE / 256, 256, 0, stream>>>(ei, cur, srtj);
    k_edge<<<NN / 4, 256, 0, stream>>>(q, ad1, as1, v, off, srtj,
                                       P2, p2, A1, A2, a2, p1, Wout, bout, out);
}

// Round 2
// 875.342 us; speedup vs baseline: 1.4720x; 1.4720x over previous
//
#include <hip/hip_runtime.h>
#include <hip/hip_bf16.h>

#define NN 65536
#define NE 1048576

typedef __attribute__((ext_vector_type(8))) short short8;
typedef __attribute__((ext_vector_type(4))) float f32x4;

__device__ __forceinline__ float bcast(float v, int l) {
    return __int_as_float(__builtin_amdgcn_readlane(__float_as_int(v), l));
}
__device__ __forceinline__ float lrelu(float x) { return x > 0.f ? x : 0.01f * x; }
__device__ __forceinline__ float frelu(float x) { return x > 0.f ? x : 0.f; }
__device__ __forceinline__ short f2bf(float f) {   // RTNE float->bf16
    unsigned u = __float_as_uint(f);
    u += 0x7fffu + ((u >> 16) & 1u);
    return (short)(u >> 16);
}

// ---- combined weights: Wda = W_dst@A1, Wsa = W_src@A1 ----
__global__ void k_prep(const float* __restrict__ Wdst, const float* __restrict__ Wsrc,
                       const float* __restrict__ A1, float* __restrict__ Wda,
                       float* __restrict__ Wsa) {
    int o = blockIdx.x * 256 + threadIdx.x;           // 0..8191
    const float* Wsel = (o < 4096) ? Wdst : Wsrc;
    float* Osel = (o < 4096) ? Wda : Wsa;
    int oo = o & 4095;
    int r = oo >> 6, c = oo & 63;
    float acc = 0.f;
#pragma unroll
    for (int k = 0; k < 64; ++k) acc += Wsel[r * 64 + k] * A1[k * 64 + c];
    Osel[oo] = acc;
}

// ---- pack P2/A1/A2 into MFMA A-fragment layout (transposed compute) ----
// A[m][k] = W[in = 32*s + 8*(l>>4) + b][out = 16*rb + (l&15)]
__global__ void k_pack(const float* __restrict__ P2, const float* __restrict__ A1,
                       const float* __restrict__ A2, short* __restrict__ Apack) {
    int idx = blockIdx.x * 256 + threadIdx.x;   // 0..1535 = ((L*4+rb)*2+s)*64 + l
    if (idx >= 1536) return;
    int l = idx & 63, s = (idx >> 6) & 1, rb = (idx >> 7) & 3, L = idx >> 9;
    const float* W = (L == 0) ? P2 : (L == 1) ? A1 : A2;
#pragma unroll
    for (int b = 0; b < 8; ++b) {
        int in = 32 * s + 8 * (l >> 4) + b;
        int out = 16 * rb + (l & 15);
        Apack[idx * 8 + b] = f2bf(W[in * 64 + out]);
    }
}

// ---- h = relu(x @ W_in + b_in) ----
__global__ void __launch_bounds__(256) k_h(const float* __restrict__ x,
                                           const float* __restrict__ Win,
                                           const float* __restrict__ bin,
                                           float* __restrict__ h) {
    __shared__ float W[4096];
    for (int idx = threadIdx.x; idx < 4096; idx += 256) W[idx] = Win[idx];
    __syncthreads();
    int wave = threadIdx.x >> 6, lane = threadIdx.x & 63;
    int n = blockIdx.x * 4 + wave;
    float xv = x[n * 64 + lane];
    float acc = bin[lane];
#pragma unroll
    for (int k = 0; k < 64; ++k) acc += bcast(xv, k) * W[k * 64 + lane];
    h[n * 64 + lane] = frelu(acc);
}

// ---- v = h@W_lin ; ad1 = h@Wda + a1 ; as1 = h@Wsa ; q = pos@P1 ----
__global__ void __launch_bounds__(256) k_node(const float* __restrict__ h,
                                              const float* __restrict__ pos,
                                              const float* __restrict__ Wlin,
                                              const float* __restrict__ Wda,
                                              const float* __restrict__ Wsa,
                                              const float* __restrict__ P1,
                                              const float* __restrict__ a1,
                                              float* __restrict__ v, float* __restrict__ ad1,
                                              float* __restrict__ as1, float* __restrict__ q) {
    __shared__ float Wl[4096], Wd[4096], Ws[4096], P[192];
    for (int idx = threadIdx.x; idx < 4096; idx += 256) {
        Wl[idx] = Wlin[idx]; Wd[idx] = Wda[idx]; Ws[idx] = Wsa[idx];
    }
    if (threadIdx.x < 192) P[threadIdx.x] = P1[threadIdx.x];
    __syncthreads();
    int wave = threadIdx.x >> 6, lane = threadIdx.x & 63;
    int n = blockIdx.x * 4 + wave;
    float hv = h[n * 64 + lane];
    float av = 0.f, bv = a1[lane], cv = 0.f;
#pragma unroll
    for (int k = 0; k < 64; ++k) {
        float s = bcast(hv, k);
        av += s * Wl[k * 64 + lane];
        bv += s * Wd[k * 64 + lane];
        cv += s * Ws[k * 64 + lane];
    }
    v[n * 64 + lane] = av;
    ad1[n * 64 + lane] = bv;
    as1[n * 64 + lane] = cv;
    float p0 = pos[n * 3 + 0], p1v = pos[n * 3 + 1], p2v = pos[n * 3 + 2];
    q[n * 64 + lane] = p0 * P[lane] + p1v * P[64 + lane] + p2v * P[128 + lane];
}

// ---- CSR build (padded to 16-edge tiles) ----
__global__ void k_hist(const int* __restrict__ ei, int* __restrict__ deg) {
    int e = blockIdx.x * 256 + threadIdx.x;
    atomicAdd(&deg[ei[NE + e]], 1);
}

__global__ void k_scan(const int* __restrict__ deg, int* __restrict__ poff,
                       int* __restrict__ cur) {
    __shared__ int part[256];
    int t = threadIdx.x;
    int sum = 0;
    for (int r = 0; r < 256; ++r) sum += ((deg[t * 256 + r] + 15) >> 4) << 4;
    part[t] = sum;
    __syncthreads();
    if (t == 0) {
        int run = 0;
        for (int b = 0; b < 256; ++b) { int tmp = part[b]; part[b] = run; run += tmp; }
    }
    __syncthreads();
    int run = part[t];
    for (int r = 0; r < 256; ++r) {
        int n = t * 256 + r;
        poff[n] = run; cur[n] = run;
        run += ((deg[n] + 15) >> 4) << 4;
    }
    if (t == 255) poff[NN] = run;
}

__global__ void k_scatter(const int* __restrict__ ei, int* __restrict__ cur,
                          int* __restrict__ srtj) {
    int e = blockIdx.x * 256 + threadIdx.x;
    int i = ei[NE + e];
    int slot = atomicAdd(&cur[i], 1);
    srtj[slot] = ei[e];
}

// D-layout -> next-layer B-frag transpose via shuffles.
// X[e][c] lives at lane 16*((c&15)>>2)+e, register [c>>4][c&3].
// Target lane (g,e) slot b needs c = 32*s + 8*g + b.
__device__ __forceinline__ short8 transfrag(const f32x4* X, int s, int g, int e) {
    short8 r;
#pragma unroll
    for (int b = 0; b < 8; ++b) {
        float lo = X[2 * s][b & 3], hi = X[2 * s + 1][b & 3];
        float val = (g & 2) ? hi : lo;
        val = __shfl(val, 16 * (2 * (g & 1) + (b >> 2)) + e);
        r[b] = f2bf(val);
    }
    return r;
}

#define MFMA(a, b, c) __builtin_amdgcn_mfma_f32_16x16x32_bf16(a, b, c, 0, 0, 0)

// ---- fused edge MLP (MFMA) + register softmax + output matvec; wave per node ----
__global__ void __launch_bounds__(256) k_edge(
    const float* __restrict__ q, const float* __restrict__ ad1, const float* __restrict__ as1,
    const float* __restrict__ v, const int* __restrict__ poff, const int* __restrict__ deg,
    const int* __restrict__ srtj, const short* __restrict__ Apack,
    const float* __restrict__ p2b, const float* __restrict__ a2b,
    const float* __restrict__ p1b, const float* __restrict__ Wout,
    const float* __restrict__ bout, float* __restrict__ out) {
    __shared__ short AwLds[12288];     // 3 layers x 4 rb x 2 s x 64 lanes x 8 bf16
    __shared__ float WoutLds[4096];
    __shared__ float biasLds[256];     // [0]p2b [64]a2b [128]bout [192]p1b
    {
        const int* gA = (const int*)Apack;
        int* sA = (int*)AwLds;
        for (int i = threadIdx.x; i < 6144; i += 256) sA[i] = gA[i];
        for (int i = threadIdx.x; i < 4096; i += 256) WoutLds[i] = Wout[i];
        if (threadIdx.x < 64) {
            biasLds[threadIdx.x] = p2b[threadIdx.x];
            biasLds[64 + threadIdx.x] = a2b[threadIdx.x];
            biasLds[128 + threadIdx.x] = bout[threadIdx.x];
            biasLds[192 + threadIdx.x] = p1b[threadIdx.x];
        }
    }
    __syncthreads();   // the only block barrier

    int l = threadIdx.x & 63;
    int g = l >> 4, e = l & 15;
    int node = blockIdx.x * 4 + (threadIdx.x >> 6);

    int t0 = poff[node], t1 = poff[node + 1];
    int dn = deg[node];

#define AW(L, rb, s) (*(const short8*)(AwLds + ((((L) * 4 + (rb)) * 2 + (s)) * 64 + l) * 8))

    // per-node hoisted values (c-pattern = 16*rb + 4*g + r)
    const float* qi = q + (size_t)node * 64;
    f32x4 qpsA0 = *(const f32x4*)(qi + 8 * g)      + *(const f32x4*)(biasLds + 192 + 8 * g);
    f32x4 qpsA1 = *(const f32x4*)(qi + 8 * g + 4)  + *(const f32x4*)(biasLds + 196 + 8 * g);
    f32x4 qpsB0 = *(const f32x4*)(qi + 32 + 8 * g) + *(const f32x4*)(biasLds + 224 + 8 * g);
    f32x4 qpsB1 = *(const f32x4*)(qi + 36 + 8 * g) + *(const f32x4*)(biasLds + 228 + 8 * g);
    f32x4 advv[4], p2c[4], a2c[4];
    const float* ai = ad1 + (size_t)node * 64;
#pragma unroll
    for (int rb = 0; rb < 4; ++rb) {
        advv[rb] = *(const f32x4*)(ai + 16 * rb + 4 * g);
        p2c[rb] = *(const f32x4*)(biasLds + 16 * rb + 4 * g);
        a2c[rb] = *(const f32x4*)(biasLds + 64 + 16 * rb + 4 * g);
    }

    f32x4 num[4], den[4];
#pragma unroll
    for (int rb = 0; rb < 4; ++rb) { num[rb] = (f32x4)0.f; den[rb] = (f32x4)0.f; }

    for (int tb = t0; tb < t1; tb += 16) {
        int j = srtj[tb + e];
        const float* qj = q + (size_t)j * 64;
        f32x4 xA0 = *(const f32x4*)(qj + 8 * g);
        f32x4 xA1 = *(const f32x4*)(qj + 8 * g + 4);
        f32x4 xB0 = *(const f32x4*)(qj + 32 + 8 * g);
        f32x4 xB1 = *(const f32x4*)(qj + 36 + 8 * g);
        short8 bu0, bu1;
#pragma unroll
        for (int b = 0; b < 4; ++b) {
            bu0[b]     = f2bf(lrelu(qpsA0[b] - xA0[b]));
            bu0[b + 4] = f2bf(lrelu(qpsA1[b] - xA1[b]));
            bu1[b]     = f2bf(lrelu(qpsB0[b] - xB0[b]));
            bu1[b + 4] = f2bf(lrelu(qpsB1[b] - xB1[b]));
        }

        // ---- layer 1: d^T = P2^T u^T + p2b ----
        f32x4 acc[4];
#pragma unroll
        for (int rb = 0; rb < 4; ++rb) acc[rb] = p2c[rb];
#pragma unroll
        for (int rb = 0; rb < 4; ++rb) {
            acc[rb] = MFMA(AW(0, rb, 0), bu0, acc[rb]);
            acc[rb] = MFMA(AW(0, rb, 1), bu1, acc[rb]);
        }
        f32x4 d4[4];
#pragma unroll
        for (int rb = 0; rb < 4; ++rb)
#pragma unroll
            for (int c = 0; c < 4; ++c) { float xx = acc[rb][c]; d4[rb][c] = xx > 0.f ? xx : 0.01f * xx; }

        // ---- layer 2: t^T = A1^T d^T + (adv_i - as1_j) ----
        short8 bd0 = transfrag(d4, 0, g, e);
        short8 bd1 = transfrag(d4, 1, g, e);
        const float* ap = as1 + (size_t)j * 64;
#pragma unroll
        for (int rb = 0; rb < 4; ++rb)
            acc[rb] = advv[rb] - *(const f32x4*)(ap + 16 * rb + 4 * g);
#pragma unroll
        for (int rb = 0; rb < 4; ++rb) {
            acc[rb] = MFMA(AW(1, rb, 0), bd0, acc[rb]);
            acc[rb] = MFMA(AW(1, rb, 1), bd1, acc[rb]);
        }
        f32x4 t4[4];
#pragma unroll
        for (int rb = 0; rb < 4; ++rb)
#pragma unroll
            for (int c = 0; c < 4; ++c) t4[rb][c] = frelu(acc[rb][c]);

        // ---- layer 3: alpha^T = A2^T t^T + a2b ----
        short8 bt0 = transfrag(t4, 0, g, e);
        short8 bt1 = transfrag(t4, 1, g, e);
#pragma unroll
        for (int rb = 0; rb < 4; ++rb) acc[rb] = a2c[rb];
#pragma unroll
        for (int rb = 0; rb < 4; ++rb) {
            acc[rb] = MFMA(AW(2, rb, 0), bt0, acc[rb]);
            acc[rb] = MFMA(AW(2, rb, 1), bt1, acc[rb]);
        }

        // ---- softmax accumulate (alpha >= 0 so exp never overflows; no max pass) ----
        bool ok = (tb - t0 + e) < dn;
        const float* vp = v + (size_t)j * 64;
#pragma unroll
        for (int rb = 0; rb < 4; ++rb) {
            f32x4 vv = *(const f32x4*)(vp + 16 * rb + 4 * g);
            f32x4 ew;
#pragma unroll
            for (int c = 0; c < 4; ++c) {
                float a = frelu(acc[rb][c]);
                ew[c] = ok ? __expf(a) : 0.f;
            }
            den[rb] += ew;
            num[rb] += ew * (vv + d4[rb]);
        }
    }

    // reduce over the 16 edge-lanes (butterfly on lane bits 0..3)
#pragma unroll
    for (int m = 1; m < 16; m <<= 1) {
#pragma unroll
        for (int rb = 0; rb < 4; ++rb)
#pragma unroll
            for (int c = 0; c < 4; ++c) {
                num[rb][c] += __shfl_xor(num[rb][c], m);
                den[rb][c] += __shfl_xor(den[rb][c], m);
            }
    }
    f32x4 o[4];
#pragma unroll
    for (int rb = 0; rb < 4; ++rb)
#pragma unroll
        for (int c = 0; c < 4; ++c) o[rb][c] = num[rb][c] / (den[rb][c] + 1e-16f);

    // out = relu(o @ Wout + bout); o[ch k] sits at lane 16*((k&15)>>2), reg [k>>4][k&3]
    float f = biasLds[128 + l];
#pragma unroll
    for (int k = 0; k < 64; ++k)
        f += bcast(o[k >> 4][k & 3], 16 * ((k & 15) >> 2)) * WoutLds[k * 64 + l];
    out[(size_t)node * 64 + l] = frelu(f);
#undef AW
}

extern "C" void kernel_launch(void* const* d_in, const int* in_sizes, int n_in,
                              void* d_out, int out_size, void* d_ws, size_t ws_size,
                              hipStream_t stream) {
    const float* x    = (const float*)d_in[0];
    const float* pos  = (const float*)d_in[1];
    const int*   ei   = (const int*)d_in[2];
    const float* Win  = (const float*)d_in[3];
    const float* bin  = (const float*)d_in[4];
    const float* Wout = (const float*)d_in[5];
    const float* bout = (const float*)d_in[6];
    const float* Wlin = (const float*)d_in[7];
    const float* Wsrc = (const float*)d_in[8];
    const float* Wdst = (const float*)d_in[9];
    const float* P1   = (const float*)d_in[10];
    const float* p1   = (const float*)d_in[11];
    const float* P2   = (const float*)d_in[12];
    const float* p2   = (const float*)d_in[13];
    const float* A1   = (const float*)d_in[14];
    const float* a1   = (const float*)d_in[15];
    const float* A2   = (const float*)d_in[16];
    const float* a2   = (const float*)d_in[17];
    float* out = (float*)d_out;

    char* w = (char*)d_ws;
    float* Wda  = (float*)w; w += 4096 * 4;
    float* Wsa  = (float*)w; w += 4096 * 4;
    short* Apck = (short*)w; w += 12288 * 2;
    float* h    = (float*)w; w += (size_t)NN * 64 * 4;
    float* v    = (float*)w; w += (size_t)NN * 64 * 4;
    float* ad1  = (float*)w; w += (size_t)NN * 64 * 4;
    float* as1  = (float*)w; w += (size_t)NN * 64 * 4;
    float* q    = (float*)w; w += (size_t)NN * 64 * 4;
    int* deg    = (int*)w; w += (size_t)NN * 4;
    int* poffp  = (int*)w; w += (size_t)(NN + 16) * 4;
    int* cur    = (int*)w; w += (size_t)NN * 4;
    int* srtj   = (int*)w; w += (size_t)2 * NE * 4;

    hipMemsetAsync(deg, 0, (size_t)NN * 4, stream);
    hipMemsetAsync(srtj, 0, (size_t)2 * NE * 4, stream);
    k_prep<<<32, 256, 0, stream>>>(Wdst, Wsrc, A1, Wda, Wsa);
    k_pack<<<6, 256, 0, stream>>>(P2, A1, A2, Apck);
    k_h<<<NN / 4, 256, 0, stream>>>(x, Win, bin, h);
    k_node<<<NN / 4, 256, 0, stream>>>(h, pos, Wlin, Wda, Wsa, P1, a1, v, ad1, as1, q);
    k_hist<<<NE / 256, 256, 0, stream>>>(ei, deg);
    k_scan<<<1, 256, 0, stream>>>(deg, poffp, cur);
    k_scatter<<<NE / 256, 256, 0, stream>>>(ei, cur, srtj);
    k_edge<<<NN / 4, 256, 0, stream>>>(q, ad1, as1, v, poffp, deg, srtj, Apck,
                                       p2, a2, p1, Wout, bout, out);
}